// Round 7
// baseline (94.386 us; speedup 1.0000x reference)
//
#include <hip/hip_runtime.h>
#include <hip/hip_bf16.h>
#include <math.h>

#define PSZ   147456           // pixels per sample (384*384)
#define NTOT  1179648          // 8 * PSZ
#define WW    384
#define HH    384
#define NIMG  8
#define NBINH 2048             // histogram bins, width 1/256, covers e in (0,8)
#define INF2F 294913.0f        // H*H + W*W + 1
#define GRF   3072             // k_fused blocks (one per image-row)
#define BPS   384              // k_fused blocks per sample
#define HBLK  576              // hist blocks (72 per sample)
#define HPXB  2048             // pixels per hist block

// ---- exact, contraction-proof helpers ----
static __device__ __forceinline__ float errval(float x, float z) {
    float s = __fsub_rn(__fmul_rn(2.0f, z), 1.0f);   // exactly +-1
    return __fsub_rn(1.0f, __fmul_rn(x, s));
}
static __device__ __forceinline__ int binof(float e) {
    int b = (int)(__fmul_rn(e, 256.0f));
    return b > (NBINH - 1) ? (NBINH - 1) : b;
}
static __device__ __forceinline__ float d2f(int d) {  // exact: d<=600 -> d*d < 2^24
    return (float)(d * d);
}

// nearest set-bit distance from column p for mask m (fg) AND ~m (bg), one pass.
// Row is exactly 384 bits = 6 u64 words; returns distances clamped to 600.
struct DPair { int df, db; };
static __device__ __forceinline__ DPair ndist2(const unsigned long long* __restrict__ m, int p) {
    const int BIG = 1 << 20;
    int q = p >> 6, b = p & 63;
    int df = BIG, db = BIG;
    {   // right scan (bits >= p, incl. self)
        unsigned long long w = m[q];
        unsigned long long tf = w >> b;
        unsigned long long tb = (~w) >> b;
        if (tf) df = __builtin_ctzll(tf);
        if (tb) db = __builtin_ctzll(tb);
        for (int u = q + 1; (df == BIG || db == BIG) && u < 6; ++u) {
            w = m[u];
            if (df == BIG && w)  df = u * 64 + __builtin_ctzll(w)  - p;
            if (db == BIG && ~w) db = u * 64 + __builtin_ctzll(~w) - p;
        }
    }
    {   // left scan (bits <= p, incl. self)
        unsigned long long w = m[q];
        unsigned long long tf = w << (63 - b);
        unsigned long long tb = (~w) << (63 - b);
        int lf = BIG, lb = BIG;
        if (tf) lf = __builtin_clzll(tf);
        if (tb) lb = __builtin_clzll(tb);
        for (int u = q - 1; (lf == BIG || lb == BIG) && u >= 0; --u) {
            w = m[u];
            if (lf == BIG && w)  lf = p - (u * 64 + 63 - __builtin_clzll(w));
            if (lb == BIG && ~w) lb = p - (u * 64 + 63 - __builtin_clzll(~w));
        }
        if (lf < df) df = lf;
        if (lb < db) db = lb;
    }
    DPair r;
    r.df = (df > 600) ? 600 : df;
    r.db = (db > 600) ? 600 : db;
    return r;
}

// ---- K1: build per-row fg bitmasks (8 img x 384 rows x 6 u64) ----
__global__ __launch_bounds__(256) void k_mask(const float* __restrict__ tgt,
                                              unsigned long long* __restrict__ gmask) {
    int row = blockIdx.x * 4 + (threadIdx.x >> 6);   // img*384 + i
    int l = threadIdx.x & 63;
    const float* tr = tgt + (size_t)row * WW;
    unsigned long long mf[6];
#pragma unroll
    for (int c = 0; c < 6; ++c)
        mf[c] = __ballot(tr[c * 64 + l] > 0.5f);     // wave-uniform
#pragma unroll
    for (int c = 0; c < 6; ++c)
        if (l == c) gmask[(size_t)row * 6 + c] = mf[c];
}

// ---- K2: fused EDT-from-bitmasks + elementwise + reductions (1 row per block) ----
__global__ __launch_bounds__(384) void k_fused(const float* __restrict__ pred,
                                               const float* __restrict__ tgt,
                                               const unsigned long long* __restrict__ gmask,
                                               float* __restrict__ pB, float* __restrict__ pP,
                                               float* __restrict__ pPT, float* __restrict__ pBnd,
                                               unsigned int* __restrict__ pPc,
                                               unsigned int* __restrict__ maxabsBits) {
    __shared__ unsigned long long lmask[128][6];     // 6 KB row-mask window
    int t = threadIdx.x;                             // column j
    int img = blockIdx.x / HH;
    int i   = blockIdx.x % HH;
    const unsigned long long* gm = gmask + (size_t)img * HH * 6;
    int iw0 = i - 63;
    if (iw0 < 0) iw0 = 0;
    if (iw0 > HH - 128) iw0 = HH - 128;              // window covers all |r|<=63
    for (int q = t; q < 128 * 6; q += 384)
        ((unsigned long long*)lmask)[q] = gm[(size_t)iw0 * 6 + q];
    __syncthreads();
    // EDT: row 0 then outward, all from LDS bit math (exact)
    DPair d0 = ndist2(&lmask[i - iw0][0], t);
    float aF = d2f(d0.df), aB = d2f(d0.db);
    for (int r = 1; r < HH; ++r) {
        float r2 = d2f(r);
        if (r2 >= aF && r2 >= aB) break;             // exact termination
        int up = i - r, dn = i + r;
        if (r <= 63) {                               // always in LDS window
            if (up >= 0) {
                DPair d = ndist2(&lmask[up - iw0][0], t);
                aF = fminf(aF, r2 + d2f(d.df));
                aB = fminf(aB, r2 + d2f(d.db));
            }
            if (dn < HH) {
                DPair d = ndist2(&lmask[dn - iw0][0], t);
                aF = fminf(aF, r2 + d2f(d.df));
                aB = fminf(aB, r2 + d2f(d.db));
            }
        } else {                                     // pathological fallback (never on this data)
            if (up >= 0) {
                DPair d = ndist2(gm + (size_t)up * 6, t);
                aF = fminf(aF, r2 + d2f(d.df));
                aB = fminf(aB, r2 + d2f(d.db));
            }
            if (dn < HH) {
                DPair d = ndist2(gm + (size_t)dn * 6, t);
                aF = fminf(aF, r2 + d2f(d.df));
                aB = fminf(aB, r2 + d2f(d.db));
            }
        }
    }
    int n = img * PSZ + i * WW + t;
    float x = pred[n], z = tgt[n];
    bool lab = z > 0.5f;
    float dv = lab ? -sqrtf(fminf(aB, INF2F)) : sqrtf(fminf(aF, INF2F));
    float bce = fmaxf(x, 0.0f) - x * z + log1pf(expf(-fabsf(x)));
    float p = 1.0f / (1.0f + expf(-x));
    // wave butterfly reductions (fixed order -> deterministic)
    float vals[6];
    vals[0] = bce; vals[1] = p; vals[2] = lab ? p : 0.0f;
    vals[3] = p * dv; vals[4] = lab ? 1.0f : 0.0f; vals[5] = fabsf(dv);
#pragma unroll
    for (int k = 0; k < 5; ++k)
#pragma unroll
        for (int off = 32; off; off >>= 1) vals[k] += __shfl_xor(vals[k], off);
#pragma unroll
    for (int off = 32; off; off >>= 1) vals[5] = fmaxf(vals[5], __shfl_xor(vals[5], off));
    __shared__ float sw[6][6];
    int wv = t >> 6, lnn = t & 63;
    if (lnn == 0) {
#pragma unroll
        for (int k = 0; k < 6; ++k) sw[wv][k] = vals[k];
    }
    __syncthreads();
    if (t < 6) {
        int k = t;
        if (k == 5) {
            float a = sw[0][5];
#pragma unroll
            for (int w = 1; w < 6; ++w) a = fmaxf(a, sw[w][5]);
            atomicMax(maxabsBits, __float_as_uint(a));
        } else {
            float a = sw[0][k];
#pragma unroll
            for (int w = 1; w < 6; ++w) a += sw[w][k];
            if (k == 0) pB[blockIdx.x] = a;
            else if (k == 1) pP[blockIdx.x] = a;
            else if (k == 2) pPT[blockIdx.x] = a;
            else if (k == 3) pBnd[blockIdx.x] = a;
            else pPc[blockIdx.x] = (unsigned int)(a + 0.5f);
        }
    }
}

// ---- K3: LDS-aggregated error histogram (packed u64: count<<46 | sum(e*2^24)) ----
__global__ __launch_bounds__(1024) void k_hist(const float* __restrict__ pred,
                                               const float* __restrict__ tgt,
                                               unsigned long long* __restrict__ hist) {
    __shared__ unsigned long long h[NBINH * 2];      // 32 KB
    for (int q = threadIdx.x; q < NBINH * 2; q += 1024) h[q] = 0ull;
    __syncthreads();
    int base = blockIdx.x * HPXB;
#pragma unroll
    for (int it = 0; it < HPXB / 1024; ++it) {       // 2 iterations
        int n = base + it * 1024 + threadIdx.x;
        float x = pred[n], z = tgt[n];
        float e = errval(x, z);
        if (e > 0.0f) {
            int lab = (z > 0.5f) ? 1 : 0;
            int bin = binof(e);
            unsigned long long add = (1ull << 46) |
                (unsigned long long)__fmul_rn(e, 16777216.0f);
            atomicAdd(&h[(bin << 1) + lab], add);
        }
    }
    __syncthreads();
    int s = blockIdx.x / (HBLK / NIMG);               // 72 blocks per sample
    unsigned long long* gh = hist + ((size_t)s * NBINH << 1);
    for (int q = threadIdx.x; q < NBINH * 2; q += 1024) {
        unsigned long long v = h[q];
        if (v) atomicAdd(&gh[q], v);                  // integer add: deterministic
    }
}

// ---- K4: per-sample bin scan -> Lovasz via binned-tie closed form ----
__global__ __launch_bounds__(256) void k_scanlov(const unsigned long long* __restrict__ hist,
                                                 const unsigned int* __restrict__ pPc,
                                                 double* __restrict__ pLovD,
                                                 unsigned int* __restrict__ Pfin) {
    int b = blockIdx.x, t = threadIdx.x;
    __shared__ unsigned int sred[256];
    unsigned int ps = 0;
    for (int q = t; q < BPS; q += 256) ps += pPc[b * BPS + q];
    sred[t] = ps; __syncthreads();
    for (int s = 128; s > 0; s >>= 1) { if (t < s) sred[t] += sred[t + s]; __syncthreads(); }
    unsigned int Pfull = sred[0];
    if (t == 0) Pfin[b] = Pfull;
    __syncthreads();
    double P = (double)Pfull;
    const unsigned long long* hc = hist + ((size_t)b * NBINH << 1);
    __shared__ unsigned int sN[257], sP2[257];
    unsigned int ln = 0, lp = 0;
    int m0 = t * (NBINH / 256);                      // 8 bins per thread
    for (int m = m0; m < m0 + NBINH / 256; ++m) {
        ln += (unsigned int)(hc[2 * m] >> 46);
        lp += (unsigned int)(hc[2 * m + 1] >> 46);
    }
    sN[t] = ln; sP2[t] = lp;
    __syncthreads();
    if (t == 0) {
        unsigned int aN = 0, aP = 0;
        for (int q = 0; q < 256; ++q) {
            unsigned int nn = sN[q], pp = sP2[q];
            sN[q] = aN; sP2[q] = aP;
            aN += nn; aP += pp;
        }
        sN[256] = aN; sP2[256] = aP;
    }
    __syncthreads();
    unsigned int totN = sN[256], totP = sP2[256];
    unsigned int runN = sN[t], runP = sP2[t];        // counts in bins < m
    const double EPS = 1e-7;
    const double SCL = 1.0 / 16777216.0;
    const unsigned long long MSK = (1ull << 46) - 1;
    double l = 0.0;
    for (int m = m0; m < m0 + NBINH / 256; ++m) {
        unsigned long long vn = hc[2 * m], vp = hc[2 * m + 1];
        unsigned int hn = (unsigned int)(vn >> 46), hp = (unsigned int)(vp >> 46);
        if (hn | hp) {
            double negAbove = (double)(totN - runN - hn);   // negatives in higher bins
            double D0 = P + negAbove + EPS;
            if (hp) {
                double sp = (double)(vp & MSK) * SCL;
                l += sp / D0;                                // bin positives share denom
            }
            if (hn) {
                double sn = (double)(vn & MSK) * SCL;
                double pAbove = (double)(totP - runP);       // positives ranked above group
                double D1 = D0 + (double)hn;
                l += (P - pAbove) * (sn / (double)hn) * (1.0 / D0 - 1.0 / D1);
            }
            runN += hn; runP += hp;
        }
    }
    __shared__ double dred[256];
    dred[t] = l; __syncthreads();
    for (int s = 128; s > 0; s >>= 1) { if (t < s) dred[t] += dred[t + s]; __syncthreads(); }
    if (t == 0) pLovD[b] = dred[0];
}

// ---- K5: final combine (deterministic f64 reduce of partials) ----
__global__ __launch_bounds__(256) void k_final(const float* __restrict__ pB, const float* __restrict__ pP,
                                               const float* __restrict__ pPT, const float* __restrict__ pBnd,
                                               const double* __restrict__ pLovD,
                                               const unsigned int* __restrict__ Pfin,
                                               const unsigned int* __restrict__ maxabsBits,
                                               float* __restrict__ out) {
    __shared__ double red[256];
    __shared__ double res[4];
    const float* arrs[4] = {pB, pP, pPT, pBnd};
    int t = threadIdx.x;
    for (int a = 0; a < 4; ++a) {
        double sum = 0.0;
        for (int q = t; q < GRF; q += 256) sum += (double)arrs[a][q];
        red[t] = sum; __syncthreads();
        for (int s = 128; s > 0; s >>= 1) { if (t < s) red[t] += red[t + s]; __syncthreads(); }
        if (t == 0) res[a] = red[0];
        __syncthreads();
    }
    if (t == 0) {
        double sumBCE = res[0], sumP = res[1], sumPT = res[2], sumBD = res[3];
        double tsum = 0.0, sumLV = 0.0;
        for (int b = 0; b < NIMG; ++b) { tsum += (double)Pfin[b]; sumLV += pLovD[b]; }
        double bce = sumBCE / (double)NTOT;
        double dice = 1.0 - (2.0 * sumPT + 1.0) / (sumP + tsum + 1.0);
        float ma = __uint_as_float(maxabsBits[0]);
        double bnd = sumBD / (double)NTOT;
        if (ma > 0.0f) bnd = bnd / (double)ma;
        double lov = sumLV / (double)NIMG;
        double loss = 0.3 * bce + 0.3 * dice + 0.2 * bnd + 0.2 * lov;
        if (loss < 0.0) loss = 0.0;
        if (loss > 100.0) loss = 100.0;
        out[0] = (float)loss;
    }
}

extern "C" void kernel_launch(void* const* d_in, const int* in_sizes, int n_in,
                              void* d_out, int out_size, void* d_ws, size_t ws_size,
                              hipStream_t stream) {
    const float* pred = (const float*)d_in[0];
    const float* tgt  = (const float*)d_in[1];
    char* ws = (char*)d_ws;

    size_t off = 0;
    unsigned long long* hist = (unsigned long long*)(ws + off); off += (size_t)NIMG * NBINH * 2 * 8; // 256 KB
    unsigned int* maxabsBits = (unsigned int*)(ws + off); off += 64;
    size_t zeroBytes = off;
    off = (off + 1023) & ~(size_t)1023;
    double* pLovD = (double*)(ws + off); off += NIMG * 8;
    unsigned int* Pfin = (unsigned int*)(ws + off); off += NIMG * 4;
    off = (off + 63) & ~(size_t)63;
    float* pB   = (float*)(ws + off); off += (size_t)GRF * 4;
    float* pP   = (float*)(ws + off); off += (size_t)GRF * 4;
    float* pPT  = (float*)(ws + off); off += (size_t)GRF * 4;
    float* pBnd = (float*)(ws + off); off += (size_t)GRF * 4;
    unsigned int* pPc = (unsigned int*)(ws + off); off += (size_t)GRF * 4;
    off = (off + 1023) & ~(size_t)1023;
    unsigned long long* gmask = (unsigned long long*)(ws + off); off += (size_t)NIMG * HH * 6 * 8; // 147 KB
    (void)off; (void)ws_size; (void)in_sizes; (void)n_in; (void)out_size;

    hipMemsetAsync(d_ws, 0, zeroBytes, stream);
    k_mask<<<NIMG * HH / 4, 256, 0, stream>>>(tgt, gmask);
    k_fused<<<GRF, 384, 0, stream>>>(pred, tgt, gmask, pB, pP, pPT, pBnd, pPc, maxabsBits);
    k_hist<<<HBLK, 1024, 0, stream>>>(pred, tgt, hist);
    k_scanlov<<<NIMG, 256, 0, stream>>>(hist, pPc, pLovD, Pfin);
    k_final<<<1, 256, 0, stream>>>(pB, pP, pPT, pBnd, pLovD, Pfin, maxabsBits, (float*)d_out);
}